// Round 2
// baseline (572.028 us; speedup 1.0000x reference)
//
#include <hip/hip_runtime.h>
#include <math.h>

// ---------------- Cl(3,0,1) compile-time algebra helpers ----------------
constexpr int cpopc(int x){ int c=0; while(x){ c += x&1; x >>= 1; } return c; }

// sign of e_a * e_b geometric product (0 if it hits the null direction e3)
constexpr float csign(int a, int b){
    if (a & b & 8) return 0.0f;   // e3^2 = 0 (metric {1,1,1,0})
    int s = 0;
    for (int t = a >> 1; t; t >>= 1) s += cpopc(t & b);
    return (s & 1) ? -1.0f : 1.0f;
}

// even subalgebra (grades 0,2,4) blade indices and inverse map
__device__ constexpr int EVEN[8] = {0,3,5,6,9,10,12,15};
__device__ constexpr int EIDX[16] = {0,-1,-1,1,-1,2,3,-1,-1,4,5,-1,6,-1,-1,7};
// reverse signs on even blades: g=0:+, g=2:-, g=4:+
__device__ constexpr float REVE[8] = {1.f,-1.f,-1.f,-1.f,-1.f,-1.f,-1.f,1.f};

// native clang vector for nontemporal builtins (HIP float4 is a struct, rejected)
typedef float vf4 __attribute__((ext_vector_type(4)));

// Grade-block workspace layout per batch row l (floats).
// Motor conjugation is grade-preserving, so T is block-diagonal:
//   [0..16)   G1: rows = input blades {1,2,4,8},        cols = {1,2,4,8}
//   [16..64)  G2: rows = input blades {3,5,6,9,10,12} x 8 (cols {3,5,6,9,10,12},pad,pad)
//   [64..80)  G3: rows = input blades {7,11,13,14},     cols = {7,11,13,14}
//   [80]      T00 = |M|^2 (scalar gain; T[15][15] identical but row 15 is overwritten)
//   [84..104) color tables: (v1,v2) float2 x 10 centers
#define WS_STRIDE 112   // 448 B, 16B-aligned per row

// ---------------- setup: per-l motor -> grade-block matrices, color tables ----------------
__global__ void setup_kernel(const float* __restrict__ instr,
                             const float* __restrict__ remap,   // [K,10,10]
                             const float* __restrict__ selw,    // [K,2]
                             const float* __restrict__ selb,    // [K]
                             float* __restrict__ ws,
                             int B, int K) {
    const int l = blockIdx.x * blockDim.x + threadIdx.x;
    if (l >= B) return;
    const float* ins = instr + l * 16;

    // x = -0.5 * grade2(instruction), even-subalgebra coords (bivectors are m=1..6)
    float bv[8];
    bv[0] = 0.f; bv[7] = 0.f;
    #pragma unroll
    for (int m = 1; m < 7; m++) bv[m] = -0.5f * ins[EVEN[m]];

    // Taylor exp, 16 terms, even subalgebra only
    float term[8], acc[8];
    #pragma unroll
    for (int m = 0; m < 8; m++){ term[m] = (m==0) ? 1.f : 0.f; acc[m] = term[m]; }
    #pragma unroll
    for (int n = 1; n < 16; n++){
        float nt[8];
        #pragma unroll
        for (int m = 0; m < 8; m++) nt[m] = 0.f;
        #pragma unroll
        for (int ia = 0; ia < 8; ia++){
            #pragma unroll
            for (int ib = 0; ib < 8; ib++){
                const float s = csign(EVEN[ia], EVEN[ib]);   // compile-time constant
                if (s != 0.f) nt[EIDX[EVEN[ia] ^ EVEN[ib]]] += s * term[ia] * bv[ib];
            }
        }
        const float inv = 1.0f / (float)n;
        #pragma unroll
        for (int m = 0; m < 8; m++){ term[m] = nt[m] * inv; acc[m] += term[m]; }
    }

    // M and ~M (even coords), pairwise products
    float P[64];
    #pragma unroll
    for (int ia = 0; ia < 8; ia++)
        #pragma unroll
        for (int ib = 0; ib < 8; ib++)
            P[ia*8+ib] = acc[ia] * (acc[ib] * REVE[ib]);

    // T[j][k] = sum_{a,b even} csign(a,j)*csign(a^j,b) * M[a]*Mrev[b], k = j^a^b
    // Only the grade-diagonal blocks are (non-residually) nonzero; store those.
    float* o = ws + (size_t)l * WS_STRIDE;
    #pragma unroll
    for (int j = 0; j < 15; j++){            // row 15 not needed (overwritten by occupancy)
        float Trow[16];
        #pragma unroll
        for (int k = 0; k < 16; k++) Trow[k] = 0.f;
        #pragma unroll
        for (int ia = 0; ia < 8; ia++){
            const int A = EVEN[ia];
            const float sa = csign(A, j);
            if (sa != 0.f){
                #pragma unroll
                for (int ib = 0; ib < 8; ib++){
                    const int Bb = EVEN[ib];
                    const float s = sa * csign(A ^ j, Bb);
                    if (s != 0.f) Trow[j ^ A ^ Bb] += s * P[ia*8+ib];
                }
            }
        }
        if (j == 0){
            o[80] = Trow[0];                 // scalar gain |M|^2
        } else {
            const int g = cpopc(j);          // compile-time (loop unrolled)
            if (g == 1){
                const int r = (j==1)?0:((j==2)?1:((j==4)?2:3));
                o[4*r+0]=Trow[1]; o[4*r+1]=Trow[2]; o[4*r+2]=Trow[4]; o[4*r+3]=Trow[8];
            } else if (g == 2){
                const int r = (j==3)?0:((j==5)?1:((j==6)?2:((j==9)?3:((j==10)?4:5))));
                float* p = o + 16 + 8*r;
                p[0]=Trow[3]; p[1]=Trow[5];  p[2]=Trow[6];  p[3]=Trow[9];
                p[4]=Trow[10]; p[5]=Trow[12]; p[6]=0.f; p[7]=0.f;
            } else { // g == 3
                const int r = (j==7)?0:((j==11)?1:((j==13)?2:3));
                float* p = o + 64 + 4*r;
                p[0]=Trow[7]; p[1]=Trow[11]; p[2]=Trow[13]; p[3]=Trow[14];
            }
        }
    }

    // ---- color tables: softmax selector weights, fold blended into v1/v2 ----
    const float s0 = ins[0], s1 = ins[15];
    float w[8];                       // K <= 8 (K=4 here)
    float mx = -1e30f;
    for (int k = 0; k < K; k++){
        w[k] = s0 * selw[2*k] + s1 * selw[2*k+1] + selb[k];
        mx = fmaxf(mx, w[k]);
    }
    float Z = 0.f;
    for (int k = 0; k < K; k++){ w[k] = __expf(w[k] - mx); Z += w[k]; }
    const float rZ = 1.f / Z;
    for (int k = 0; k < K; k++) w[k] *= rZ;

    // v1[i] = sum_j blended[i][j]*j/9 ; v2[i] = blended[i][0]; interleaved float2
    for (int i = 0; i < 10; i++){
        float a1 = 0.f, a2 = 0.f;
        for (int k = 0; k < K; k++){
            const float* rk = remap + (size_t)(k*10 + i) * 10;
            float rd = 0.f;
            #pragma unroll
            for (int j = 0; j < 10; j++) rd += rk[j] * (float)j;
            a1 += w[k] * rd;
            a2 += w[k] * rk[0];
        }
        o[84 + 2*i]     = a1 * (1.f / 9.f);
        o[84 + 2*i + 1] = a2;
    }
}

// ---------------- main streaming kernel ----------------
#define TPB 256
#define EPT 2

__device__ __forceinline__ void transform_one(
    const float* sW,
    const float4 a0, const float4 a1, const float4 a2, const float4 a3,
    float4& o0, float4& o1, float4& o2, float4& o3)
{
    // blades: a0=(x0,x1,x2,x3) a1=(x4,x5,x6,x7) a2=(x8,x9,x10,x11) a3=(x12,x13,x14,x15)

    // ---- grade-1 block (inputs x1,x2,x4,x8) ----
    const float4 g10 = *reinterpret_cast<const float4*>(sW + 0);
    const float4 g11 = *reinterpret_cast<const float4*>(sW + 4);
    const float4 g12 = *reinterpret_cast<const float4*>(sW + 8);
    const float4 g13 = *reinterpret_cast<const float4*>(sW + 12);
    const float y1 = a0.y*g10.x + a0.z*g11.x + a1.x*g12.x + a2.x*g13.x;
    const float y2 = a0.y*g10.y + a0.z*g11.y + a1.x*g12.y + a2.x*g13.y;
    const float y4 = a0.y*g10.z + a0.z*g11.z + a1.x*g12.z + a2.x*g13.z;
    const float y8 = a0.y*g10.w + a0.z*g11.w + a1.x*g12.w + a2.x*g13.w;

    // ---- grade-2 block (inputs x3,x5,x6,x9,x10,x12) ----
    float y3, y5, y6, y9, y10, y12;
    {
        const float4 ra = *reinterpret_cast<const float4*>(sW + 16);
        const float2 rb = *reinterpret_cast<const float2*>(sW + 20);
        y3  = a0.w*ra.x; y5  = a0.w*ra.y; y6  = a0.w*ra.z; y9 = a0.w*ra.w;
        y10 = a0.w*rb.x; y12 = a0.w*rb.y;
    }
    {
        const float4 ra = *reinterpret_cast<const float4*>(sW + 24);
        const float2 rb = *reinterpret_cast<const float2*>(sW + 28);
        y3  += a1.y*ra.x; y5  += a1.y*ra.y; y6  += a1.y*ra.z; y9 += a1.y*ra.w;
        y10 += a1.y*rb.x; y12 += a1.y*rb.y;
    }
    {
        const float4 ra = *reinterpret_cast<const float4*>(sW + 32);
        const float2 rb = *reinterpret_cast<const float2*>(sW + 36);
        y3  += a1.z*ra.x; y5  += a1.z*ra.y; y6  += a1.z*ra.z; y9 += a1.z*ra.w;
        y10 += a1.z*rb.x; y12 += a1.z*rb.y;
    }
    {
        const float4 ra = *reinterpret_cast<const float4*>(sW + 40);
        const float2 rb = *reinterpret_cast<const float2*>(sW + 44);
        y3  += a2.y*ra.x; y5  += a2.y*ra.y; y6  += a2.y*ra.z; y9 += a2.y*ra.w;
        y10 += a2.y*rb.x; y12 += a2.y*rb.y;
    }
    {
        const float4 ra = *reinterpret_cast<const float4*>(sW + 48);
        const float2 rb = *reinterpret_cast<const float2*>(sW + 52);
        y3  += a2.z*ra.x; y5  += a2.z*ra.y; y6  += a2.z*ra.z; y9 += a2.z*ra.w;
        y10 += a2.z*rb.x; y12 += a2.z*rb.y;
    }
    {
        const float4 ra = *reinterpret_cast<const float4*>(sW + 56);
        const float2 rb = *reinterpret_cast<const float2*>(sW + 60);
        y3  += a3.x*ra.x; y5  += a3.x*ra.y; y6  += a3.x*ra.z; y9 += a3.x*ra.w;
        y10 += a3.x*rb.x; y12 += a3.x*rb.y;
    }

    // ---- grade-3 block (inputs x7,x11,x13,x14) ----
    const float4 g30 = *reinterpret_cast<const float4*>(sW + 64);
    const float4 g31 = *reinterpret_cast<const float4*>(sW + 68);
    const float4 g32 = *reinterpret_cast<const float4*>(sW + 72);
    const float4 g33 = *reinterpret_cast<const float4*>(sW + 76);
    const float y7  = a1.w*g30.x + a2.w*g31.x + a3.y*g32.x + a3.z*g33.x;
    const float y11 = a1.w*g30.y + a2.w*g31.y + a3.y*g32.y + a3.z*g33.y;
    const float y13 = a1.w*g30.z + a2.w*g31.z + a3.y*g32.z + a3.z*g33.z;
    const float y14 = a1.w*g30.w + a2.w*g31.w + a3.y*g32.w + a3.z*g33.w;

    // ---- color unit: stable softmax over 10 centers, folded into two dot products ----
    const float raw  = (sW[80] * a0.x) * 9.f;                 // spatial[0] = T00 * x0
    const float ncf  = fminf(fmaxf(rintf(raw), 0.f), 9.f);    // nearest center => max logit
    const float dmin = raw - ncf;
    const float mlog = -4.f * dmin * dmin;
    float Z = 0.f, c1 = 0.f, c2 = 0.f;
    #pragma unroll
    for (int i = 0; i < 10; i++){
        const float d  = raw - (float)i;
        const float ev = __expf(-4.f*d*d - mlog);
        const float2 v = reinterpret_cast<const float2*>(sW + 84)[i];
        Z += ev; c1 += ev * v.x; c2 += ev * v.y;
    }
    const float rZ = 1.f / Z;

    o0 = make_float4(c1 * rZ, y1,  y2,  y3);
    o1 = make_float4(y4,      y5,  y6,  y7);
    o2 = make_float4(y8,      y9,  y10, y11);
    o3 = make_float4(y12,     y13, y14, 1.f - c2 * rZ);
}

__device__ __forceinline__ void nt_store4(float4* p, const float4& v){
    __builtin_nontemporal_store(*reinterpret_cast<const vf4*>(&v),
                                reinterpret_cast<vf4*>(p));
}

__global__ __launch_bounds__(TPB, 4) void apply_kernel(
    const float* __restrict__ state, const float* __restrict__ ws,
    float* __restrict__ out, int N)
{
    const int l = blockIdx.y;
    __shared__ float sW[WS_STRIDE];
    if (threadIdx.x < WS_STRIDE/4)
        reinterpret_cast<float4*>(sW)[threadIdx.x] =
            reinterpret_cast<const float4*>(ws + (size_t)l * WS_STRIDE)[threadIdx.x];
    __syncthreads();

    const int tid    = blockIdx.x * TPB + threadIdx.x;
    const int stride = gridDim.x * TPB;
    const float4* __restrict__ sp = reinterpret_cast<const float4*>(state) + (size_t)l * N * 4;
    float4*       __restrict__ op = reinterpret_cast<float4*>(out)        + (size_t)l * N * 4;

    const int n0 = tid;
    const int n1 = tid + stride;
    const bool v0 = n0 < N;
    const bool v1 = n1 < N;

    // issue both elements' loads up front for memory-level parallelism
    float4 a0,a1,a2,a3, b0,b1,b2,b3;
    if (v0){
        const float4* p = sp + (size_t)n0 * 4;
        a0 = p[0]; a1 = p[1]; a2 = p[2]; a3 = p[3];
    } else {
        a0 = a1 = a2 = a3 = make_float4(0.f,0.f,0.f,0.f);
    }
    if (v1){
        const float4* p = sp + (size_t)n1 * 4;
        b0 = p[0]; b1 = p[1]; b2 = p[2]; b3 = p[3];
    } else {
        b0 = b1 = b2 = b3 = make_float4(0.f,0.f,0.f,0.f);
    }

    float4 o0,o1,o2,o3, q0,q1,q2,q3;
    transform_one(sW, a0,a1,a2,a3, o0,o1,o2,o3);
    transform_one(sW, b0,b1,b2,b3, q0,q1,q2,q3);

    // streaming (non-temporal) stores: don't let the 200MB output stream evict
    // the L3-resident input between iterations
    if (v0){
        float4* p = op + (size_t)n0 * 4;
        nt_store4(p+0, o0); nt_store4(p+1, o1);
        nt_store4(p+2, o2); nt_store4(p+3, o3);
    }
    if (v1){
        float4* p = op + (size_t)n1 * 4;
        nt_store4(p+0, q0); nt_store4(p+1, q1);
        nt_store4(p+2, q2); nt_store4(p+3, q3);
    }
}

extern "C" void kernel_launch(void* const* d_in, const int* in_sizes, int n_in,
                              void* d_out, int out_size, void* d_ws, size_t ws_size,
                              hipStream_t stream) {
    const float* state = (const float*)d_in[0];
    const float* instr = (const float*)d_in[1];
    const float* remap = (const float*)d_in[2];
    const float* selw  = (const float*)d_in[3];
    const float* selb  = (const float*)d_in[4];
    float* ws  = (float*)d_ws;
    float* out = (float*)d_out;

    const int B = in_sizes[1] / 16;          // 32
    const int N = in_sizes[0] / (16 * B);    // 100000
    const int K = in_sizes[4];               // 4

    setup_kernel<<<dim3((B + 63) / 64), 64, 0, stream>>>(instr, remap, selw, selb, ws, B, K);

    const int groups = (N + TPB * EPT - 1) / (TPB * EPT);   // 196
    apply_kernel<<<dim3(groups, B), TPB, 0, stream>>>(state, ws, out, N);
}

// Round 3
// 489.367 us; speedup vs baseline: 1.1689x; 1.1689x over previous
//
#include <hip/hip_runtime.h>
#include <math.h>

// ---------------- Cl(3,0,1) compile-time algebra helpers ----------------
constexpr int cpopc(int x){ int c=0; while(x){ c += x&1; x >>= 1; } return c; }

// sign of e_a * e_b geometric product (0 if it hits the null direction e3)
constexpr float csign(int a, int b){
    if (a & b & 8) return 0.0f;   // e3^2 = 0 (metric {1,1,1,0})
    int s = 0;
    for (int t = a >> 1; t; t >>= 1) s += cpopc(t & b);
    return (s & 1) ? -1.0f : 1.0f;
}

// even subalgebra (grades 0,2,4) blade indices and inverse map
__device__ constexpr int EVEN[8] = {0,3,5,6,9,10,12,15};
__device__ constexpr int EIDX[16] = {0,-1,-1,1,-1,2,3,-1,-1,4,5,-1,6,-1,-1,7};
// reverse signs on even blades: g=0:+, g=2:-, g=4:+
__device__ constexpr float REVE[8] = {1.f,-1.f,-1.f,-1.f,-1.f,-1.f,-1.f,1.f};

// Grade-block workspace layout per batch row l (floats).
// Motor conjugation is grade-preserving, so T is block-diagonal:
//   [0..16)   G1: rows = input blades {1,2,4,8},        cols = {1,2,4,8}
//   [16..64)  G2: rows = input blades {3,5,6,9,10,12} x 8 (cols {3,5,6,9,10,12},pad,pad)
//   [64..80)  G3: rows = input blades {7,11,13,14},     cols = {7,11,13,14}
//   [80]      T00 = |M|^2 (scalar gain; T[15][15] identical but row 15 is overwritten)
//   [84..104) color tables: (v1,v2) float2 x 10 centers
#define WS_STRIDE 112   // 448 B, 16B-aligned per row

// ---------------- setup: per-l motor -> grade-block matrices, color tables ----------------
__global__ void setup_kernel(const float* __restrict__ instr,
                             const float* __restrict__ remap,   // [K,10,10]
                             const float* __restrict__ selw,    // [K,2]
                             const float* __restrict__ selb,    // [K]
                             float* __restrict__ ws,
                             int B, int K) {
    const int l = blockIdx.x * blockDim.x + threadIdx.x;
    if (l >= B) return;
    const float* ins = instr + l * 16;

    // x = -0.5 * grade2(instruction), even-subalgebra coords (bivectors are m=1..6)
    float bv[8];
    bv[0] = 0.f; bv[7] = 0.f;
    #pragma unroll
    for (int m = 1; m < 7; m++) bv[m] = -0.5f * ins[EVEN[m]];

    // Taylor exp, 16 terms, even subalgebra only
    float term[8], acc[8];
    #pragma unroll
    for (int m = 0; m < 8; m++){ term[m] = (m==0) ? 1.f : 0.f; acc[m] = term[m]; }
    #pragma unroll
    for (int n = 1; n < 16; n++){
        float nt[8];
        #pragma unroll
        for (int m = 0; m < 8; m++) nt[m] = 0.f;
        #pragma unroll
        for (int ia = 0; ia < 8; ia++){
            #pragma unroll
            for (int ib = 0; ib < 8; ib++){
                const float s = csign(EVEN[ia], EVEN[ib]);   // compile-time constant
                if (s != 0.f) nt[EIDX[EVEN[ia] ^ EVEN[ib]]] += s * term[ia] * bv[ib];
            }
        }
        const float inv = 1.0f / (float)n;
        #pragma unroll
        for (int m = 0; m < 8; m++){ term[m] = nt[m] * inv; acc[m] += term[m]; }
    }

    // M and ~M (even coords), pairwise products
    float P[64];
    #pragma unroll
    for (int ia = 0; ia < 8; ia++)
        #pragma unroll
        for (int ib = 0; ib < 8; ib++)
            P[ia*8+ib] = acc[ia] * (acc[ib] * REVE[ib]);

    // T[j][k] = sum_{a,b even} csign(a,j)*csign(a^j,b) * M[a]*Mrev[b], k = j^a^b
    // Only the grade-diagonal blocks are (non-residually) nonzero; store those.
    float* o = ws + (size_t)l * WS_STRIDE;
    #pragma unroll
    for (int j = 0; j < 15; j++){            // row 15 not needed (overwritten by occupancy)
        float Trow[16];
        #pragma unroll
        for (int k = 0; k < 16; k++) Trow[k] = 0.f;
        #pragma unroll
        for (int ia = 0; ia < 8; ia++){
            const int A = EVEN[ia];
            const float sa = csign(A, j);
            if (sa != 0.f){
                #pragma unroll
                for (int ib = 0; ib < 8; ib++){
                    const int Bb = EVEN[ib];
                    const float s = sa * csign(A ^ j, Bb);
                    if (s != 0.f) Trow[j ^ A ^ Bb] += s * P[ia*8+ib];
                }
            }
        }
        if (j == 0){
            o[80] = Trow[0];                 // scalar gain |M|^2
        } else {
            const int g = cpopc(j);          // compile-time (loop unrolled)
            if (g == 1){
                const int r = (j==1)?0:((j==2)?1:((j==4)?2:3));
                o[4*r+0]=Trow[1]; o[4*r+1]=Trow[2]; o[4*r+2]=Trow[4]; o[4*r+3]=Trow[8];
            } else if (g == 2){
                const int r = (j==3)?0:((j==5)?1:((j==6)?2:((j==9)?3:((j==10)?4:5))));
                float* p = o + 16 + 8*r;
                p[0]=Trow[3]; p[1]=Trow[5];  p[2]=Trow[6];  p[3]=Trow[9];
                p[4]=Trow[10]; p[5]=Trow[12]; p[6]=0.f; p[7]=0.f;
            } else { // g == 3
                const int r = (j==7)?0:((j==11)?1:((j==13)?2:3));
                float* p = o + 64 + 4*r;
                p[0]=Trow[7]; p[1]=Trow[11]; p[2]=Trow[13]; p[3]=Trow[14];
            }
        }
    }

    // ---- color tables: softmax selector weights, fold blended into v1/v2 ----
    const float s0 = ins[0], s1 = ins[15];
    float w[8];                       // K <= 8 (K=4 here)
    float mx = -1e30f;
    for (int k = 0; k < K; k++){
        w[k] = s0 * selw[2*k] + s1 * selw[2*k+1] + selb[k];
        mx = fmaxf(mx, w[k]);
    }
    float Z = 0.f;
    for (int k = 0; k < K; k++){ w[k] = __expf(w[k] - mx); Z += w[k]; }
    const float rZ = 1.f / Z;
    for (int k = 0; k < K; k++) w[k] *= rZ;

    // v1[i] = sum_j blended[i][j]*j/9 ; v2[i] = blended[i][0]; interleaved float2
    for (int i = 0; i < 10; i++){
        float a1 = 0.f, a2 = 0.f;
        for (int k = 0; k < K; k++){
            const float* rk = remap + (size_t)(k*10 + i) * 10;
            float rd = 0.f;
            #pragma unroll
            for (int j = 0; j < 10; j++) rd += rk[j] * (float)j;
            a1 += w[k] * rd;
            a2 += w[k] * rk[0];
        }
        o[84 + 2*i]     = a1 * (1.f / 9.f);
        o[84 + 2*i + 1] = a2;
    }
}

// ---------------- main streaming kernel ----------------
#define TPB 256
#define EPT 2

__device__ __forceinline__ void transform_one(
    const float* sW,
    const float4 a0, const float4 a1, const float4 a2, const float4 a3,
    float4& o0, float4& o1, float4& o2, float4& o3)
{
    // blades: a0=(x0,x1,x2,x3) a1=(x4,x5,x6,x7) a2=(x8,x9,x10,x11) a3=(x12,x13,x14,x15)

    // ---- grade-1 block (inputs x1,x2,x4,x8) ----
    const float4 g10 = *reinterpret_cast<const float4*>(sW + 0);
    const float4 g11 = *reinterpret_cast<const float4*>(sW + 4);
    const float4 g12 = *reinterpret_cast<const float4*>(sW + 8);
    const float4 g13 = *reinterpret_cast<const float4*>(sW + 12);
    const float y1 = a0.y*g10.x + a0.z*g11.x + a1.x*g12.x + a2.x*g13.x;
    const float y2 = a0.y*g10.y + a0.z*g11.y + a1.x*g12.y + a2.x*g13.y;
    const float y4 = a0.y*g10.z + a0.z*g11.z + a1.x*g12.z + a2.x*g13.z;
    const float y8 = a0.y*g10.w + a0.z*g11.w + a1.x*g12.w + a2.x*g13.w;

    // ---- grade-2 block (inputs x3,x5,x6,x9,x10,x12) ----
    float y3, y5, y6, y9, y10, y12;
    {
        const float4 ra = *reinterpret_cast<const float4*>(sW + 16);
        const float2 rb = *reinterpret_cast<const float2*>(sW + 20);
        y3  = a0.w*ra.x; y5  = a0.w*ra.y; y6  = a0.w*ra.z; y9 = a0.w*ra.w;
        y10 = a0.w*rb.x; y12 = a0.w*rb.y;
    }
    {
        const float4 ra = *reinterpret_cast<const float4*>(sW + 24);
        const float2 rb = *reinterpret_cast<const float2*>(sW + 28);
        y3  += a1.y*ra.x; y5  += a1.y*ra.y; y6  += a1.y*ra.z; y9 += a1.y*ra.w;
        y10 += a1.y*rb.x; y12 += a1.y*rb.y;
    }
    {
        const float4 ra = *reinterpret_cast<const float4*>(sW + 32);
        const float2 rb = *reinterpret_cast<const float2*>(sW + 36);
        y3  += a1.z*ra.x; y5  += a1.z*ra.y; y6  += a1.z*ra.z; y9 += a1.z*ra.w;
        y10 += a1.z*rb.x; y12 += a1.z*rb.y;
    }
    {
        const float4 ra = *reinterpret_cast<const float4*>(sW + 40);
        const float2 rb = *reinterpret_cast<const float2*>(sW + 44);
        y3  += a2.y*ra.x; y5  += a2.y*ra.y; y6  += a2.y*ra.z; y9 += a2.y*ra.w;
        y10 += a2.y*rb.x; y12 += a2.y*rb.y;
    }
    {
        const float4 ra = *reinterpret_cast<const float4*>(sW + 48);
        const float2 rb = *reinterpret_cast<const float2*>(sW + 52);
        y3  += a2.z*ra.x; y5  += a2.z*ra.y; y6  += a2.z*ra.z; y9 += a2.z*ra.w;
        y10 += a2.z*rb.x; y12 += a2.z*rb.y;
    }
    {
        const float4 ra = *reinterpret_cast<const float4*>(sW + 56);
        const float2 rb = *reinterpret_cast<const float2*>(sW + 60);
        y3  += a3.x*ra.x; y5  += a3.x*ra.y; y6  += a3.x*ra.z; y9 += a3.x*ra.w;
        y10 += a3.x*rb.x; y12 += a3.x*rb.y;
    }

    // ---- grade-3 block (inputs x7,x11,x13,x14) ----
    const float4 g30 = *reinterpret_cast<const float4*>(sW + 64);
    const float4 g31 = *reinterpret_cast<const float4*>(sW + 68);
    const float4 g32 = *reinterpret_cast<const float4*>(sW + 72);
    const float4 g33 = *reinterpret_cast<const float4*>(sW + 76);
    const float y7  = a1.w*g30.x + a2.w*g31.x + a3.y*g32.x + a3.z*g33.x;
    const float y11 = a1.w*g30.y + a2.w*g31.y + a3.y*g32.y + a3.z*g33.y;
    const float y13 = a1.w*g30.z + a2.w*g31.z + a3.y*g32.z + a3.z*g33.z;
    const float y14 = a1.w*g30.w + a2.w*g31.w + a3.y*g32.w + a3.z*g33.w;

    // ---- color unit: stable softmax over 10 centers, folded into two dot products ----
    const float raw  = (sW[80] * a0.x) * 9.f;                 // spatial[0] = T00 * x0
    const float ncf  = fminf(fmaxf(rintf(raw), 0.f), 9.f);    // nearest center => max logit
    const float dmin = raw - ncf;
    const float mlog = -4.f * dmin * dmin;
    float Z = 0.f, c1 = 0.f, c2 = 0.f;
    #pragma unroll
    for (int i = 0; i < 10; i++){
        const float d  = raw - (float)i;
        const float ev = __expf(-4.f*d*d - mlog);
        const float2 v = reinterpret_cast<const float2*>(sW + 84)[i];
        Z += ev; c1 += ev * v.x; c2 += ev * v.y;
    }
    const float rZ = 1.f / Z;

    o0 = make_float4(c1 * rZ, y1,  y2,  y3);
    o1 = make_float4(y4,      y5,  y6,  y7);
    o2 = make_float4(y8,      y9,  y10, y11);
    o3 = make_float4(y12,     y13, y14, 1.f - c2 * rZ);
}

__global__ __launch_bounds__(TPB, 4) void apply_kernel(
    const float* __restrict__ state, const float* __restrict__ ws,
    float* __restrict__ out, int N)
{
    const int l = blockIdx.y;
    __shared__ float sW[WS_STRIDE];
    if (threadIdx.x < WS_STRIDE/4)
        reinterpret_cast<float4*>(sW)[threadIdx.x] =
            reinterpret_cast<const float4*>(ws + (size_t)l * WS_STRIDE)[threadIdx.x];
    __syncthreads();

    const int tid    = blockIdx.x * TPB + threadIdx.x;
    const int stride = gridDim.x * TPB;
    const float4* __restrict__ sp = reinterpret_cast<const float4*>(state) + (size_t)l * N * 4;
    float4*       __restrict__ op = reinterpret_cast<float4*>(out)        + (size_t)l * N * 4;

    const int n0 = tid;
    const int n1 = tid + stride;
    const bool v0 = n0 < N;
    const bool v1 = n1 < N;

    // issue both elements' loads up front for memory-level parallelism
    float4 a0,a1,a2,a3, b0,b1,b2,b3;
    if (v0){
        const float4* p = sp + (size_t)n0 * 4;
        a0 = p[0]; a1 = p[1]; a2 = p[2]; a3 = p[3];
    } else {
        a0 = a1 = a2 = a3 = make_float4(0.f,0.f,0.f,0.f);
    }
    if (v1){
        const float4* p = sp + (size_t)n1 * 4;
        b0 = p[0]; b1 = p[1]; b2 = p[2]; b3 = p[3];
    } else {
        b0 = b1 = b2 = b3 = make_float4(0.f,0.f,0.f,0.f);
    }

    float4 o0,o1,o2,o3, q0,q1,q2,q3;
    transform_one(sW, a0,a1,a2,a3, o0,o1,o2,o3);
    transform_one(sW, b0,b1,b2,b3, q0,q1,q2,q3);

    // plain cached stores: the 4 interleaved dwordx4 per element write-combine
    // in L2 (round-0/2 A/B: cached = exactly 200MB WRITE, nt = 553MB from
    // uncombined partial-line streaming)
    if (v0){
        float4* p = op + (size_t)n0 * 4;
        p[0] = o0; p[1] = o1; p[2] = o2; p[3] = o3;
    }
    if (v1){
        float4* p = op + (size_t)n1 * 4;
        p[0] = q0; p[1] = q1; p[2] = q2; p[3] = q3;
    }
}

extern "C" void kernel_launch(void* const* d_in, const int* in_sizes, int n_in,
                              void* d_out, int out_size, void* d_ws, size_t ws_size,
                              hipStream_t stream) {
    const float* state = (const float*)d_in[0];
    const float* instr = (const float*)d_in[1];
    const float* remap = (const float*)d_in[2];
    const float* selw  = (const float*)d_in[3];
    const float* selb  = (const float*)d_in[4];
    float* ws  = (float*)d_ws;
    float* out = (float*)d_out;

    const int B = in_sizes[1] / 16;          // 32
    const int N = in_sizes[0] / (16 * B);    // 100000
    const int K = in_sizes[4];               // 4

    setup_kernel<<<dim3((B + 63) / 64), 64, 0, stream>>>(instr, remap, selw, selb, ws, B, K);

    const int groups = (N + TPB * EPT - 1) / (TPB * EPT);   // 196
    apply_kernel<<<dim3(groups, B), TPB, 0, stream>>>(state, ws, out, N);
}

// Round 4
// 451.982 us; speedup vs baseline: 1.2656x; 1.0827x over previous
//
#include <hip/hip_runtime.h>
#include <math.h>

// ---------------- Cl(3,0,1) compile-time algebra helpers ----------------
constexpr int cpopc(int x){ int c=0; while(x){ c += x&1; x >>= 1; } return c; }

// sign of e_a * e_b geometric product (0 if it hits the null direction e3)
constexpr float csign(int a, int b){
    if (a & b & 8) return 0.0f;   // e3^2 = 0 (metric {1,1,1,0})
    int s = 0;
    for (int t = a >> 1; t; t >>= 1) s += cpopc(t & b);
    return (s & 1) ? -1.0f : 1.0f;
}

// even subalgebra (grades 0,2,4) blade indices and inverse map
__device__ constexpr int EVEN[8] = {0,3,5,6,9,10,12,15};
__device__ constexpr int EIDX[16] = {0,-1,-1,1,-1,2,3,-1,-1,4,5,-1,6,-1,-1,7};
// reverse signs on even blades: g=0:+, g=2:-, g=4:+
__device__ constexpr float REVE[8] = {1.f,-1.f,-1.f,-1.f,-1.f,-1.f,-1.f,1.f};

// Grade-block workspace layout per batch row l (floats).
// Motor conjugation is grade-preserving, so T is block-diagonal:
//   [0..16)   G1: rows = input blades {1,2,4,8},        cols = {1,2,4,8}
//   [16..64)  G2: rows = input blades {3,5,6,9,10,12} x 8 (cols {3,5,6,9,10,12},pad,pad)
//   [64..80)  G3: rows = input blades {7,11,13,14},     cols = {7,11,13,14}
//   [80]      T00 = |M|^2 (scalar gain; T[15][15] identical but row 15 is overwritten)
//   [84..104) color tables: (v1,v2) float2 x 10 centers
#define WS_STRIDE 112   // 448 B, 16B-aligned per row

// ---------------- setup: per-l motor -> grade-block matrices, color tables ----------------
__global__ void setup_kernel(const float* __restrict__ instr,
                             const float* __restrict__ remap,   // [K,10,10]
                             const float* __restrict__ selw,    // [K,2]
                             const float* __restrict__ selb,    // [K]
                             float* __restrict__ ws,
                             int B, int K) {
    const int l = blockIdx.x * blockDim.x + threadIdx.x;
    if (l >= B) return;
    const float* ins = instr + l * 16;

    // x = -0.5 * grade2(instruction), even-subalgebra coords (bivectors are m=1..6)
    float bv[8];
    bv[0] = 0.f; bv[7] = 0.f;
    #pragma unroll
    for (int m = 1; m < 7; m++) bv[m] = -0.5f * ins[EVEN[m]];

    // Taylor exp, 16 terms, even subalgebra only
    float term[8], acc[8];
    #pragma unroll
    for (int m = 0; m < 8; m++){ term[m] = (m==0) ? 1.f : 0.f; acc[m] = term[m]; }
    #pragma unroll
    for (int n = 1; n < 16; n++){
        float nt[8];
        #pragma unroll
        for (int m = 0; m < 8; m++) nt[m] = 0.f;
        #pragma unroll
        for (int ia = 0; ia < 8; ia++){
            #pragma unroll
            for (int ib = 0; ib < 8; ib++){
                const float s = csign(EVEN[ia], EVEN[ib]);   // compile-time constant
                if (s != 0.f) nt[EIDX[EVEN[ia] ^ EVEN[ib]]] += s * term[ia] * bv[ib];
            }
        }
        const float inv = 1.0f / (float)n;
        #pragma unroll
        for (int m = 0; m < 8; m++){ term[m] = nt[m] * inv; acc[m] += term[m]; }
    }

    // M and ~M (even coords), pairwise products
    float P[64];
    #pragma unroll
    for (int ia = 0; ia < 8; ia++)
        #pragma unroll
        for (int ib = 0; ib < 8; ib++)
            P[ia*8+ib] = acc[ia] * (acc[ib] * REVE[ib]);

    // T[j][k] = sum_{a,b even} csign(a,j)*csign(a^j,b) * M[a]*Mrev[b], k = j^a^b
    // Only the grade-diagonal blocks are (non-residually) nonzero; store those.
    float* o = ws + (size_t)l * WS_STRIDE;
    #pragma unroll
    for (int j = 0; j < 15; j++){            // row 15 not needed (overwritten by occupancy)
        float Trow[16];
        #pragma unroll
        for (int k = 0; k < 16; k++) Trow[k] = 0.f;
        #pragma unroll
        for (int ia = 0; ia < 8; ia++){
            const int A = EVEN[ia];
            const float sa = csign(A, j);
            if (sa != 0.f){
                #pragma unroll
                for (int ib = 0; ib < 8; ib++){
                    const int Bb = EVEN[ib];
                    const float s = sa * csign(A ^ j, Bb);
                    if (s != 0.f) Trow[j ^ A ^ Bb] += s * P[ia*8+ib];
                }
            }
        }
        if (j == 0){
            o[80] = Trow[0];                 // scalar gain |M|^2
        } else {
            const int g = cpopc(j);          // compile-time (loop unrolled)
            if (g == 1){
                const int r = (j==1)?0:((j==2)?1:((j==4)?2:3));
                o[4*r+0]=Trow[1]; o[4*r+1]=Trow[2]; o[4*r+2]=Trow[4]; o[4*r+3]=Trow[8];
            } else if (g == 2){
                const int r = (j==3)?0:((j==5)?1:((j==6)?2:((j==9)?3:((j==10)?4:5))));
                float* p = o + 16 + 8*r;
                p[0]=Trow[3]; p[1]=Trow[5];  p[2]=Trow[6];  p[3]=Trow[9];
                p[4]=Trow[10]; p[5]=Trow[12]; p[6]=0.f; p[7]=0.f;
            } else { // g == 3
                const int r = (j==7)?0:((j==11)?1:((j==13)?2:3));
                float* p = o + 64 + 4*r;
                p[0]=Trow[7]; p[1]=Trow[11]; p[2]=Trow[13]; p[3]=Trow[14];
            }
        }
    }

    // ---- color tables: softmax selector weights, fold blended into v1/v2 ----
    const float s0 = ins[0], s1 = ins[15];
    float w[8];                       // K <= 8 (K=4 here)
    float mx = -1e30f;
    for (int k = 0; k < K; k++){
        w[k] = s0 * selw[2*k] + s1 * selw[2*k+1] + selb[k];
        mx = fmaxf(mx, w[k]);
    }
    float Z = 0.f;
    for (int k = 0; k < K; k++){ w[k] = __expf(w[k] - mx); Z += w[k]; }
    const float rZ = 1.f / Z;
    for (int k = 0; k < K; k++) w[k] *= rZ;

    // v1[i] = sum_j blended[i][j]*j/9 ; v2[i] = blended[i][0]; interleaved float2
    for (int i = 0; i < 10; i++){
        float a1 = 0.f, a2 = 0.f;
        for (int k = 0; k < K; k++){
            const float* rk = remap + (size_t)(k*10 + i) * 10;
            float rd = 0.f;
            #pragma unroll
            for (int j = 0; j < 10; j++) rd += rk[j] * (float)j;
            a1 += w[k] * rd;
            a2 += w[k] * rk[0];
        }
        o[84 + 2*i]     = a1 * (1.f / 9.f);
        o[84 + 2*i + 1] = a2;
    }
}

// ---------------- main streaming kernel ----------------
#define TPB 256
#define CHUNK 256      // elements per LDS tile (= TPB, one element per thread)
#define CPB 2          // chunks per block

// LDS slot swizzle: element e, component c -> float4 index.
// Rotates the 4 components within the element by (e>>1), so a read of fixed c
// across consecutive lanes e hits all 8 distinct 16B slots per 128B row
// (conflict-free ds_read_b128 / ds_write_b128 on 32 banks).
__device__ __forceinline__ int swz(int e, int c){ return 4*e + ((c + (e>>1)) & 3); }

__device__ __forceinline__ void transform_one(
    const float* sW,
    const float4 a0, const float4 a1, const float4 a2, const float4 a3,
    float4& o0, float4& o1, float4& o2, float4& o3)
{
    // blades: a0=(x0,x1,x2,x3) a1=(x4,x5,x6,x7) a2=(x8,x9,x10,x11) a3=(x12,x13,x14,x15)

    // ---- grade-1 block (inputs x1,x2,x4,x8) ----
    const float4 g10 = *reinterpret_cast<const float4*>(sW + 0);
    const float4 g11 = *reinterpret_cast<const float4*>(sW + 4);
    const float4 g12 = *reinterpret_cast<const float4*>(sW + 8);
    const float4 g13 = *reinterpret_cast<const float4*>(sW + 12);
    const float y1 = a0.y*g10.x + a0.z*g11.x + a1.x*g12.x + a2.x*g13.x;
    const float y2 = a0.y*g10.y + a0.z*g11.y + a1.x*g12.y + a2.x*g13.y;
    const float y4 = a0.y*g10.z + a0.z*g11.z + a1.x*g12.z + a2.x*g13.z;
    const float y8 = a0.y*g10.w + a0.z*g11.w + a1.x*g12.w + a2.x*g13.w;

    // ---- grade-2 block (inputs x3,x5,x6,x9,x10,x12) ----
    float y3, y5, y6, y9, y10, y12;
    {
        const float4 ra = *reinterpret_cast<const float4*>(sW + 16);
        const float2 rb = *reinterpret_cast<const float2*>(sW + 20);
        y3  = a0.w*ra.x; y5  = a0.w*ra.y; y6  = a0.w*ra.z; y9 = a0.w*ra.w;
        y10 = a0.w*rb.x; y12 = a0.w*rb.y;
    }
    {
        const float4 ra = *reinterpret_cast<const float4*>(sW + 24);
        const float2 rb = *reinterpret_cast<const float2*>(sW + 28);
        y3  += a1.y*ra.x; y5  += a1.y*ra.y; y6  += a1.y*ra.z; y9 += a1.y*ra.w;
        y10 += a1.y*rb.x; y12 += a1.y*rb.y;
    }
    {
        const float4 ra = *reinterpret_cast<const float4*>(sW + 32);
        const float2 rb = *reinterpret_cast<const float2*>(sW + 36);
        y3  += a1.z*ra.x; y5  += a1.z*ra.y; y6  += a1.z*ra.z; y9 += a1.z*ra.w;
        y10 += a1.z*rb.x; y12 += a1.z*rb.y;
    }
    {
        const float4 ra = *reinterpret_cast<const float4*>(sW + 40);
        const float2 rb = *reinterpret_cast<const float2*>(sW + 44);
        y3  += a2.y*ra.x; y5  += a2.y*ra.y; y6  += a2.y*ra.z; y9 += a2.y*ra.w;
        y10 += a2.y*rb.x; y12 += a2.y*rb.y;
    }
    {
        const float4 ra = *reinterpret_cast<const float4*>(sW + 48);
        const float2 rb = *reinterpret_cast<const float2*>(sW + 52);
        y3  += a2.z*ra.x; y5  += a2.z*ra.y; y6  += a2.z*ra.z; y9 += a2.z*ra.w;
        y10 += a2.z*rb.x; y12 += a2.z*rb.y;
    }
    {
        const float4 ra = *reinterpret_cast<const float4*>(sW + 56);
        const float2 rb = *reinterpret_cast<const float2*>(sW + 60);
        y3  += a3.x*ra.x; y5  += a3.x*ra.y; y6  += a3.x*ra.z; y9 += a3.x*ra.w;
        y10 += a3.x*rb.x; y12 += a3.x*rb.y;
    }

    // ---- grade-3 block (inputs x7,x11,x13,x14) ----
    const float4 g30 = *reinterpret_cast<const float4*>(sW + 64);
    const float4 g31 = *reinterpret_cast<const float4*>(sW + 68);
    const float4 g32 = *reinterpret_cast<const float4*>(sW + 72);
    const float4 g33 = *reinterpret_cast<const float4*>(sW + 76);
    const float y7  = a1.w*g30.x + a2.w*g31.x + a3.y*g32.x + a3.z*g33.x;
    const float y11 = a1.w*g30.y + a2.w*g31.y + a3.y*g32.y + a3.z*g33.y;
    const float y13 = a1.w*g30.z + a2.w*g31.z + a3.y*g32.z + a3.z*g33.z;
    const float y14 = a1.w*g30.w + a2.w*g31.w + a3.y*g32.w + a3.z*g33.w;

    // ---- color unit: stable softmax over 10 centers, folded into two dot products ----
    const float raw  = (sW[80] * a0.x) * 9.f;                 // spatial[0] = T00 * x0
    const float ncf  = fminf(fmaxf(rintf(raw), 0.f), 9.f);    // nearest center => max logit
    const float dmin = raw - ncf;
    const float mlog = -4.f * dmin * dmin;
    float Z = 0.f, c1 = 0.f, c2 = 0.f;
    #pragma unroll
    for (int i = 0; i < 10; i++){
        const float d  = raw - (float)i;
        const float ev = __expf(-4.f*d*d - mlog);
        const float2 v = reinterpret_cast<const float2*>(sW + 84)[i];
        Z += ev; c1 += ev * v.x; c2 += ev * v.y;
    }
    const float rZ = 1.f / Z;

    o0 = make_float4(c1 * rZ, y1,  y2,  y3);
    o1 = make_float4(y4,      y5,  y6,  y7);
    o2 = make_float4(y8,      y9,  y10, y11);
    o3 = make_float4(y12,     y13, y14, 1.f - c2 * rZ);
}

__global__ __launch_bounds__(TPB, 4) void apply_kernel(
    const float* __restrict__ state, const float* __restrict__ ws,
    float* __restrict__ out, int N)
{
    const int l = blockIdx.y;
    const int t = threadIdx.x;

    __shared__ float  sW[WS_STRIDE];
    __shared__ float4 sIn [CHUNK*4];   // 16 KB staging in
    __shared__ float4 sOut[CHUNK*4];   // 16 KB staging out

    if (t < WS_STRIDE/4)
        reinterpret_cast<float4*>(sW)[t] =
            reinterpret_cast<const float4*>(ws + (size_t)l * WS_STRIDE)[t];
    // sW is consumed after the first __syncthreads below — covered.

    const float4* __restrict__ sp = reinterpret_cast<const float4*>(state) + (size_t)l * N * 4;
    float4*       __restrict__ op = reinterpret_cast<float4*>(out)         + (size_t)l * N * 4;

    const int chunk0 = blockIdx.x * CPB;

    for (int cc = 0; cc < CPB; cc++){
        const int gbase = (chunk0 + cc) * CHUNK;          // first element of this chunk
        const float4* gp = sp + (size_t)gbase * 4;
        float4*       gq = op + (size_t)gbase * 4;

        // ---- stage-in: fully coalesced global reads (1KB/wave/instr), swizzled LDS writes
        #pragma unroll
        for (int k = 0; k < 4; k++){
            const int n = k*TPB + t;                      // float4 index within chunk
            const int e = n >> 2, c = n & 3;
            float4 v = make_float4(0.f,0.f,0.f,0.f);
            if (gbase + e < N) v = gp[n];
            sIn[swz(e, c)] = v;
        }
        __syncthreads();

        // ---- compute: one element per lane, conflict-free swizzled LDS reads/writes
        {
            const float4 a0 = sIn[swz(t,0)];
            const float4 a1 = sIn[swz(t,1)];
            const float4 a2 = sIn[swz(t,2)];
            const float4 a3 = sIn[swz(t,3)];
            float4 o0,o1,o2,o3;
            transform_one(sW, a0,a1,a2,a3, o0,o1,o2,o3);
            sOut[swz(t,0)] = o0;
            sOut[swz(t,1)] = o1;
            sOut[swz(t,2)] = o2;
            sOut[swz(t,3)] = o3;
        }
        __syncthreads();

        // ---- drain: swizzled LDS reads, fully coalesced global writes.
        // Each store instruction covers contiguous full cache lines -> no
        // partial-sector RFO / write amplification regardless of L2 pressure.
        #pragma unroll
        for (int k = 0; k < 4; k++){
            const int n = k*TPB + t;
            const int e = n >> 2, c = n & 3;
            if (gbase + e < N) gq[n] = sOut[swz(e, c)];
        }
        // next iteration: stage-in(B) may overlap drain(A) (different buffers);
        // the barrier after stage-in(B) orders drain(A) before compute(B)'s
        // sOut overwrite.
    }
}

extern "C" void kernel_launch(void* const* d_in, const int* in_sizes, int n_in,
                              void* d_out, int out_size, void* d_ws, size_t ws_size,
                              hipStream_t stream) {
    const float* state = (const float*)d_in[0];
    const float* instr = (const float*)d_in[1];
    const float* remap = (const float*)d_in[2];
    const float* selw  = (const float*)d_in[3];
    const float* selb  = (const float*)d_in[4];
    float* ws  = (float*)d_ws;
    float* out = (float*)d_out;

    const int B = in_sizes[1] / 16;          // 32
    const int N = in_sizes[0] / (16 * B);    // 100000
    const int K = in_sizes[4];               // 4

    setup_kernel<<<dim3((B + 63) / 64), 64, 0, stream>>>(instr, remap, selw, selb, ws, B, K);

    const int total_chunks = (N + CHUNK - 1) / CHUNK;       // 391
    const int groups = (total_chunks + CPB - 1) / CPB;      // 196
    apply_kernel<<<dim3(groups, B), TPB, 0, stream>>>(state, ws, out, N);
}

// Round 5
// 449.143 us; speedup vs baseline: 1.2736x; 1.0063x over previous
//
#include <hip/hip_runtime.h>
#include <math.h>

// ---------------- Cl(3,0,1) compile-time algebra helpers ----------------
constexpr int cpopc(int x){ int c=0; while(x){ c += x&1; x >>= 1; } return c; }

// sign of e_a * e_b geometric product (0 if it hits the null direction e3)
constexpr float csign(int a, int b){
    if (a & b & 8) return 0.0f;   // e3^2 = 0 (metric {1,1,1,0})
    int s = 0;
    for (int t = a >> 1; t; t >>= 1) s += cpopc(t & b);
    return (s & 1) ? -1.0f : 1.0f;
}

// even subalgebra (grades 0,2,4) blade indices and inverse map
__device__ constexpr int EVEN[8] = {0,3,5,6,9,10,12,15};
__device__ constexpr int EIDX[16] = {0,-1,-1,1,-1,2,3,-1,-1,4,5,-1,6,-1,-1,7};
// reverse signs on even blades: g=0:+, g=2:-, g=4:+
__device__ constexpr float REVE[8] = {1.f,-1.f,-1.f,-1.f,-1.f,-1.f,-1.f,1.f};

// Grade-block workspace layout per batch row l (floats).
// Motor conjugation is grade-preserving, so T is block-diagonal:
//   [0..16)   G1: rows = input blades {1,2,4,8},        cols = {1,2,4,8}
//   [16..64)  G2: rows = input blades {3,5,6,9,10,12} x 8 (cols {3,5,6,9,10,12},pad,pad)
//   [64..80)  G3: rows = input blades {7,11,13,14},     cols = {7,11,13,14}
//   [80]      T00 = |M|^2 (scalar gain; T[15][15] identical but row 15 is overwritten)
//   [84..104) color tables: (v1,v2) float2 x 10 centers
#define WS_STRIDE 112   // 448 B, 16B-aligned per row

// ---------------- setup: per-l motor -> grade-block matrices, color tables ----------------
__global__ void setup_kernel(const float* __restrict__ instr,
                             const float* __restrict__ remap,   // [K,10,10]
                             const float* __restrict__ selw,    // [K,2]
                             const float* __restrict__ selb,    // [K]
                             float* __restrict__ ws,
                             int B, int K) {
    const int l = blockIdx.x * blockDim.x + threadIdx.x;
    if (l >= B) return;
    const float* ins = instr + l * 16;

    // x = -0.5 * grade2(instruction), even-subalgebra coords (bivectors are m=1..6)
    float bv[8];
    bv[0] = 0.f; bv[7] = 0.f;
    #pragma unroll
    for (int m = 1; m < 7; m++) bv[m] = -0.5f * ins[EVEN[m]];

    // Taylor exp, 16 terms, even subalgebra only
    float term[8], acc[8];
    #pragma unroll
    for (int m = 0; m < 8; m++){ term[m] = (m==0) ? 1.f : 0.f; acc[m] = term[m]; }
    #pragma unroll
    for (int n = 1; n < 16; n++){
        float nt[8];
        #pragma unroll
        for (int m = 0; m < 8; m++) nt[m] = 0.f;
        #pragma unroll
        for (int ia = 0; ia < 8; ia++){
            #pragma unroll
            for (int ib = 0; ib < 8; ib++){
                const float s = csign(EVEN[ia], EVEN[ib]);   // compile-time constant
                if (s != 0.f) nt[EIDX[EVEN[ia] ^ EVEN[ib]]] += s * term[ia] * bv[ib];
            }
        }
        const float inv = 1.0f / (float)n;
        #pragma unroll
        for (int m = 0; m < 8; m++){ term[m] = nt[m] * inv; acc[m] += term[m]; }
    }

    // M and ~M (even coords), pairwise products
    float P[64];
    #pragma unroll
    for (int ia = 0; ia < 8; ia++)
        #pragma unroll
        for (int ib = 0; ib < 8; ib++)
            P[ia*8+ib] = acc[ia] * (acc[ib] * REVE[ib]);

    // T[j][k] = sum_{a,b even} csign(a,j)*csign(a^j,b) * M[a]*Mrev[b], k = j^a^b
    // Only the grade-diagonal blocks are (non-residually) nonzero; store those.
    float* o = ws + (size_t)l * WS_STRIDE;
    #pragma unroll
    for (int j = 0; j < 15; j++){            // row 15 not needed (overwritten by occupancy)
        float Trow[16];
        #pragma unroll
        for (int k = 0; k < 16; k++) Trow[k] = 0.f;
        #pragma unroll
        for (int ia = 0; ia < 8; ia++){
            const int A = EVEN[ia];
            const float sa = csign(A, j);
            if (sa != 0.f){
                #pragma unroll
                for (int ib = 0; ib < 8; ib++){
                    const int Bb = EVEN[ib];
                    const float s = sa * csign(A ^ j, Bb);
                    if (s != 0.f) Trow[j ^ A ^ Bb] += s * P[ia*8+ib];
                }
            }
        }
        if (j == 0){
            o[80] = Trow[0];                 // scalar gain |M|^2
        } else {
            const int g = cpopc(j);          // compile-time (loop unrolled)
            if (g == 1){
                const int r = (j==1)?0:((j==2)?1:((j==4)?2:3));
                o[4*r+0]=Trow[1]; o[4*r+1]=Trow[2]; o[4*r+2]=Trow[4]; o[4*r+3]=Trow[8];
            } else if (g == 2){
                const int r = (j==3)?0:((j==5)?1:((j==6)?2:((j==9)?3:((j==10)?4:5))));
                float* p = o + 16 + 8*r;
                p[0]=Trow[3]; p[1]=Trow[5];  p[2]=Trow[6];  p[3]=Trow[9];
                p[4]=Trow[10]; p[5]=Trow[12]; p[6]=0.f; p[7]=0.f;
            } else { // g == 3
                const int r = (j==7)?0:((j==11)?1:((j==13)?2:3));
                float* p = o + 64 + 4*r;
                p[0]=Trow[7]; p[1]=Trow[11]; p[2]=Trow[13]; p[3]=Trow[14];
            }
        }
    }

    // ---- color tables: softmax selector weights, fold blended into v1/v2 ----
    const float s0 = ins[0], s1 = ins[15];
    float w[8];                       // K <= 8 (K=4 here)
    float mx = -1e30f;
    for (int k = 0; k < K; k++){
        w[k] = s0 * selw[2*k] + s1 * selw[2*k+1] + selb[k];
        mx = fmaxf(mx, w[k]);
    }
    float Z = 0.f;
    for (int k = 0; k < K; k++){ w[k] = __expf(w[k] - mx); Z += w[k]; }
    const float rZ = 1.f / Z;
    for (int k = 0; k < K; k++) w[k] *= rZ;

    // v1[i] = sum_j blended[i][j]*j/9 ; v2[i] = blended[i][0]; interleaved float2
    for (int i = 0; i < 10; i++){
        float a1 = 0.f, a2 = 0.f;
        for (int k = 0; k < K; k++){
            const float* rk = remap + (size_t)(k*10 + i) * 10;
            float rd = 0.f;
            #pragma unroll
            for (int j = 0; j < 10; j++) rd += rk[j] * (float)j;
            a1 += w[k] * rd;
            a2 += w[k] * rk[0];
        }
        o[84 + 2*i]     = a1 * (1.f / 9.f);
        o[84 + 2*i + 1] = a2;
    }
}

// ---------------- main streaming kernel ----------------
#define TPB 256
#define CHUNK 256      // elements per LDS tile (= TPB, one element per thread)
#define CPB 2          // chunks per block

// LDS slot swizzle: element e, component c -> float4 index.
// Rotates the 4 components within the element by (e>>1), so both access
// patterns (per-element fixed-c, and linear drain) hit all 8 distinct 16B
// slots per 128B row across every 8 consecutive lanes (<=2-way per 16 lanes,
// which is free on 32 banks).
__device__ __forceinline__ int swz(int e, int c){ return 4*e + ((c + (e>>1)) & 3); }

__device__ __forceinline__ void transform_one(
    const float* sW,
    const float4 a0, const float4 a1, const float4 a2, const float4 a3,
    float4& o0, float4& o1, float4& o2, float4& o3)
{
    // blades: a0=(x0,x1,x2,x3) a1=(x4,x5,x6,x7) a2=(x8,x9,x10,x11) a3=(x12,x13,x14,x15)

    // ---- grade-1 block (inputs x1,x2,x4,x8) ----
    const float4 g10 = *reinterpret_cast<const float4*>(sW + 0);
    const float4 g11 = *reinterpret_cast<const float4*>(sW + 4);
    const float4 g12 = *reinterpret_cast<const float4*>(sW + 8);
    const float4 g13 = *reinterpret_cast<const float4*>(sW + 12);
    const float y1 = a0.y*g10.x + a0.z*g11.x + a1.x*g12.x + a2.x*g13.x;
    const float y2 = a0.y*g10.y + a0.z*g11.y + a1.x*g12.y + a2.x*g13.y;
    const float y4 = a0.y*g10.z + a0.z*g11.z + a1.x*g12.z + a2.x*g13.z;
    const float y8 = a0.y*g10.w + a0.z*g11.w + a1.x*g12.w + a2.x*g13.w;

    // ---- grade-2 block (inputs x3,x5,x6,x9,x10,x12) ----
    float y3, y5, y6, y9, y10, y12;
    {
        const float4 ra = *reinterpret_cast<const float4*>(sW + 16);
        const float2 rb = *reinterpret_cast<const float2*>(sW + 20);
        y3  = a0.w*ra.x; y5  = a0.w*ra.y; y6  = a0.w*ra.z; y9 = a0.w*ra.w;
        y10 = a0.w*rb.x; y12 = a0.w*rb.y;
    }
    {
        const float4 ra = *reinterpret_cast<const float4*>(sW + 24);
        const float2 rb = *reinterpret_cast<const float2*>(sW + 28);
        y3  += a1.y*ra.x; y5  += a1.y*ra.y; y6  += a1.y*ra.z; y9 += a1.y*ra.w;
        y10 += a1.y*rb.x; y12 += a1.y*rb.y;
    }
    {
        const float4 ra = *reinterpret_cast<const float4*>(sW + 32);
        const float2 rb = *reinterpret_cast<const float2*>(sW + 36);
        y3  += a1.z*ra.x; y5  += a1.z*ra.y; y6  += a1.z*ra.z; y9 += a1.z*ra.w;
        y10 += a1.z*rb.x; y12 += a1.z*rb.y;
    }
    {
        const float4 ra = *reinterpret_cast<const float4*>(sW + 40);
        const float2 rb = *reinterpret_cast<const float2*>(sW + 44);
        y3  += a2.y*ra.x; y5  += a2.y*ra.y; y6  += a2.y*ra.z; y9 += a2.y*ra.w;
        y10 += a2.y*rb.x; y12 += a2.y*rb.y;
    }
    {
        const float4 ra = *reinterpret_cast<const float4*>(sW + 48);
        const float2 rb = *reinterpret_cast<const float2*>(sW + 52);
        y3  += a2.z*ra.x; y5  += a2.z*ra.y; y6  += a2.z*ra.z; y9 += a2.z*ra.w;
        y10 += a2.z*rb.x; y12 += a2.z*rb.y;
    }
    {
        const float4 ra = *reinterpret_cast<const float4*>(sW + 56);
        const float2 rb = *reinterpret_cast<const float2*>(sW + 60);
        y3  += a3.x*ra.x; y5  += a3.x*ra.y; y6  += a3.x*ra.z; y9 += a3.x*ra.w;
        y10 += a3.x*rb.x; y12 += a3.x*rb.y;
    }

    // ---- grade-3 block (inputs x7,x11,x13,x14) ----
    const float4 g30 = *reinterpret_cast<const float4*>(sW + 64);
    const float4 g31 = *reinterpret_cast<const float4*>(sW + 68);
    const float4 g32 = *reinterpret_cast<const float4*>(sW + 72);
    const float4 g33 = *reinterpret_cast<const float4*>(sW + 76);
    const float y7  = a1.w*g30.x + a2.w*g31.x + a3.y*g32.x + a3.z*g33.x;
    const float y11 = a1.w*g30.y + a2.w*g31.y + a3.y*g32.y + a3.z*g33.y;
    const float y13 = a1.w*g30.z + a2.w*g31.z + a3.y*g32.z + a3.z*g33.z;
    const float y14 = a1.w*g30.w + a2.w*g31.w + a3.y*g32.w + a3.z*g33.w;

    // ---- color unit: stable softmax over 10 centers, folded into two dot products ----
    const float raw  = (sW[80] * a0.x) * 9.f;                 // spatial[0] = T00 * x0
    const float ncf  = fminf(fmaxf(rintf(raw), 0.f), 9.f);    // nearest center => max logit
    const float dmin = raw - ncf;
    const float mlog = -4.f * dmin * dmin;
    float Z = 0.f, c1 = 0.f, c2 = 0.f;
    #pragma unroll
    for (int i = 0; i < 10; i++){
        const float d  = raw - (float)i;
        const float ev = __expf(-4.f*d*d - mlog);
        const float2 v = reinterpret_cast<const float2*>(sW + 84)[i];
        Z += ev; c1 += ev * v.x; c2 += ev * v.y;
    }
    const float rZ = 1.f / Z;

    o0 = make_float4(c1 * rZ, y1,  y2,  y3);
    o1 = make_float4(y4,      y5,  y6,  y7);
    o2 = make_float4(y8,      y9,  y10, y11);
    o3 = make_float4(y12,     y13, y14, 1.f - c2 * rZ);
}

// 17KB LDS + <=64 VGPR -> 8 blocks/CU (32 waves, 100% wave capacity).
// Direct global reads (partial-line loads merge in L2, no RFO cost — R0/R3
// FETCH data); LDS staging for WRITES only (partial-line stores amplified
// 1.65-2.8x in R2/R3).
__global__ __launch_bounds__(TPB, 8) void apply_kernel(
    const float* __restrict__ state, const float* __restrict__ ws,
    float* __restrict__ out, int N)
{
    const int l = blockIdx.y;
    const int t = threadIdx.x;

    __shared__ float  sW[WS_STRIDE];
    __shared__ float4 sOut[CHUNK*4];   // 16 KB staging out

    if (t < WS_STRIDE/4)
        reinterpret_cast<float4*>(sW)[t] =
            reinterpret_cast<const float4*>(ws + (size_t)l * WS_STRIDE)[t];
    __syncthreads();

    const float4* __restrict__ sp = reinterpret_cast<const float4*>(state) + (size_t)l * N * 4;
    float4*       __restrict__ op = reinterpret_cast<float4*>(out)         + (size_t)l * N * 4;

    const int chunk0 = blockIdx.x * CPB;

    for (int cc = 0; cc < CPB; cc++){
        if (cc) __syncthreads();                          // sOut free of previous drain readers
        const int gbase = (chunk0 + cc) * CHUNK;          // first element of this chunk
        const int n0 = gbase + t;                         // this thread's element

        // ---- direct global read of own element (4x dwordx4, 64B-stride lanes)
        float4 a0,a1,a2,a3;
        if (n0 < N){
            const float4* p = sp + (size_t)n0 * 4;
            a0 = p[0]; a1 = p[1]; a2 = p[2]; a3 = p[3];
        } else {
            a0 = a1 = a2 = a3 = make_float4(0.f,0.f,0.f,0.f);
        }

        // ---- compute, stash to LDS (swizzled, conflict-free)
        float4 o0,o1,o2,o3;
        transform_one(sW, a0,a1,a2,a3, o0,o1,o2,o3);
        sOut[swz(t,0)] = o0;
        sOut[swz(t,1)] = o1;
        sOut[swz(t,2)] = o2;
        sOut[swz(t,3)] = o3;
        __syncthreads();

        // ---- drain: swizzled LDS reads, fully coalesced global writes
        // (each store instruction covers contiguous full cache lines)
        float4* gq = op + (size_t)gbase * 4;
        #pragma unroll
        for (int k = 0; k < 4; k++){
            const int n = k*TPB + t;
            const int e = n >> 2, c = n & 3;
            if (gbase + e < N) gq[n] = sOut[swz(e, c)];
        }
    }
}

extern "C" void kernel_launch(void* const* d_in, const int* in_sizes, int n_in,
                              void* d_out, int out_size, void* d_ws, size_t ws_size,
                              hipStream_t stream) {
    const float* state = (const float*)d_in[0];
    const float* instr = (const float*)d_in[1];
    const float* remap = (const float*)d_in[2];
    const float* selw  = (const float*)d_in[3];
    const float* selb  = (const float*)d_in[4];
    float* ws  = (float*)d_ws;
    float* out = (float*)d_out;

    const int B = in_sizes[1] / 16;          // 32
    const int N = in_sizes[0] / (16 * B);    // 100000
    const int K = in_sizes[4];               // 4

    setup_kernel<<<dim3((B + 63) / 64), 64, 0, stream>>>(instr, remap, selw, selb, ws, B, K);

    const int total_chunks = (N + CHUNK - 1) / CHUNK;       // 391
    const int groups = (total_chunks + CPB - 1) / CPB;      // 196
    apply_kernel<<<dim3(groups, B), TPB, 0, stream>>>(state, ws, out, N);
}